// Round 8
// baseline (223.478 us; speedup 1.0000x reference)
//
#include <hip/hip_runtime.h>
#include <hip/hip_bf16.h>
#include <stdint.h>

typedef __attribute__((ext_vector_type(4))) int i32x4;
typedef __attribute__((ext_vector_type(16))) int i32x16;
typedef signed char s8;

#define M_TOT 8192
#define N_TOT 8192
#define K_TOT 2048
#define W_COUNT (N_TOT * K_TOT)
#define X_COUNT (M_TOT * K_TOT)

// ---------------- 1. fused deterministic reductions: sum|w| (double), max|x| ----------
__global__ void tl_reduce(const float* __restrict__ w, const float* __restrict__ x,
                          double* __restrict__ wsum, float* __restrict__ xmax) {
    const int b = blockIdx.x;
    if (b < 1024) {
        const int tid = b * 256 + threadIdx.x;
        const float4* w4 = (const float4*)w;
        double s = 0.0;
        for (int i = tid; i < W_COUNT / 4; i += 1024 * 256) {
            float4 v = w4[i];
            s += (double)fabsf(v.x) + (double)fabsf(v.y) + (double)fabsf(v.z) + (double)fabsf(v.w);
        }
        #pragma unroll
        for (int off = 32; off > 0; off >>= 1) s += __shfl_down(s, off);
        __shared__ double red[4];
        if ((threadIdx.x & 63) == 0) red[threadIdx.x >> 6] = s;
        __syncthreads();
        if (threadIdx.x == 0) wsum[b] = (red[0] + red[1]) + (red[2] + red[3]);
    } else {
        const int tid = (b - 1024) * 256 + threadIdx.x;
        const float4* x4 = (const float4*)x;
        float m = 0.0f;
        for (int i = tid; i < X_COUNT / 4; i += 1024 * 256) {
            float4 v = x4[i];
            m = fmaxf(m, fmaxf(fmaxf(fabsf(v.x), fabsf(v.y)), fmaxf(fabsf(v.z), fabsf(v.w))));
        }
        #pragma unroll
        for (int off = 32; off > 0; off >>= 1) m = fmaxf(m, __shfl_down(m, off));
        __shared__ float redm[4];
        if ((threadIdx.x & 63) == 0) redm[threadIdx.x >> 6] = m;
        __syncthreads();
        if (threadIdx.x == 0) xmax[b - 1024] = fmaxf(fmaxf(redm[0], redm[1]), fmaxf(redm[2], redm[3]));
    }
}

__global__ void tl_finalize(const double* __restrict__ wsum, const float* __restrict__ xmax,
                            const float* __restrict__ alpha,
                            double* __restrict__ delta, float* __restrict__ qp) {
    const int t = threadIdx.x;
    double s = (wsum[t] + wsum[t + 256]) + (wsum[t + 512] + wsum[t + 768]);
    float m = fmaxf(fmaxf(xmax[t], xmax[t + 256]), fmaxf(xmax[t + 512], xmax[t + 768]));
    #pragma unroll
    for (int off = 32; off > 0; off >>= 1) {
        s += __shfl_down(s, off);
        m = fmaxf(m, __shfl_down(m, off));
    }
    __shared__ double rs[4];
    __shared__ float rm[4];
    if ((t & 63) == 0) { rs[t >> 6] = s; rm[t >> 6] = m; }
    __syncthreads();
    if (t == 0) {
        *delta = 0.7 * (((rs[0] + rs[1]) + (rs[2] + rs[3])) / (double)W_COUNT);
        float mm = fmaxf(fmaxf(rm[0], rm[1]), fmaxf(rm[2], rm[3]));
        qp[0] = 127.0f / mm;                   // x quant scale
        qp[1] = alpha[0] * (mm / 127.0f);      // output scale
    }
}

// ---------------- 2. ternarize w -> i8 fragments (MFMA-ready layout) ----------------
// Fragment frag = NB*64 + KB (NB = n>>5, KB = k>>5): 1024 B, lane l holds
// B[NB*32 + (l&31)][KB*32 + (l>>5)*16 .. +16). Stores fully coalesced (i*16).
__global__ void tl_tern_w(const float* __restrict__ w, const double* __restrict__ delta_p,
                          s8* __restrict__ wbF) {
    const double d = *delta_p;
    const int i = blockIdx.x * 256 + threadIdx.x;     // 1,048,576 threads x 16B
    const int frag = i >> 6, lane = i & 63;
    const int n = (frag >> 6) * 32 + (lane & 31);
    const int k = (frag & 63) * 32 + (lane >> 5) * 16;
    const float* src = w + (size_t)n * K_TOT + k;
    union { s8 c[16]; i32x4 v; } o;
    #pragma unroll
    for (int j = 0; j < 16; j += 4) {
        float4 v = *(const float4*)(src + j);
        float f[4] = {v.x, v.y, v.z, v.w};
        #pragma unroll
        for (int r = 0; r < 4; ++r) {
            double wd = (double)f[r];
            o.c[j + r] = wd > d ? 1 : (wd < -d ? -1 : 0);
        }
    }
    *(i32x4*)(wbF + (size_t)i * 16) = o.v;
}

// ---------------- 3. quantize x -> i8 (RNE, clamp 127), row-major ----------------
__global__ void tl_quant_x(const float* __restrict__ x, const float* __restrict__ qp,
                           s8* __restrict__ xb) {
    const float inv = qp[0];
    const int i = (blockIdx.x * 256 + threadIdx.x) * 16;
    union { s8 c[16]; i32x4 v; } o;
    #pragma unroll
    for (int j = 0; j < 16; j += 4) {
        float4 v = *(const float4*)(x + i + j);
        float f[4] = {v.x, v.y, v.z, v.w};
        #pragma unroll
        for (int r = 0; r < 4; ++r) {
            int q = (int)__builtin_rintf(f[r] * inv);
            q = q > 127 ? 127 : (q < -127 ? -127 : q);
            o.c[j + r] = (s8)q;
        }
    }
    *(i32x4*)(xb + i) = o.v;
}

// ---------------- 4. i8 MFMA GEMM: A via LDS (3 slots), B direct L2->regs ----------
// C[m][n] = out_scale * (sum_k xq[m][k]*wt[n][k]) + bias[n]
// 512 threads = 8 waves (2 wr x 4 wc); wave owns 128x64 of C = 4x2 32x32 tiles.
// LDS: A only, 3 slots x 16KB (48 KiB). B-frags: coalesced 1KB loads from wbF.
// Per tile: 4 ds_read(h1) | 4 B-loads(t+1) | 2 glds(t+2) | VMW(8) [B(t) ready] |
// lgkm(4) | MFMA h0 | lgkm(0) | VMW(6) [slot t+1 staged] | BARR | 4 ds_read(t+1 h0)
// | MFMA h1.  vm queue invariant entering tile t: [B(t) 4, gldsA(t+1) 2].

#define SB    __builtin_amdgcn_sched_barrier(0)
#define BARR  __builtin_amdgcn_s_barrier()
#define LGKM4 asm volatile("s_waitcnt lgkmcnt(4)" ::: "memory")
#define LGKM0 asm volatile("s_waitcnt lgkmcnt(0)" ::: "memory")
#define VMW(N) asm volatile("s_waitcnt vmcnt(" #N ")" ::: "memory")
#define PRIO1 __builtin_amdgcn_s_setprio(1)
#define PRIO0 __builtin_amdgcn_s_setprio(0)

#define GLDS(SRC, DOFF) __builtin_amdgcn_global_load_lds(                      \
    (const __attribute__((address_space(1))) void*)(SRC),                      \
    (__attribute__((address_space(3))) void*)(lds + (DOFF)), 16, 0, 0)

#define RD_A4(AR, S, KK) do {                                                  \
    _Pragma("unroll") for (int m_ = 0; m_ < 4; ++m_)                           \
        AR[m_] = *(const i32x4*)(lds + (S) * 16384 + wrOff + m_ * 2048 +       \
                                 (lrd ^ ((KK) * 32)));                         \
} while (0)

// B(t+1) frags: [0]=(n0,h0) [1]=(n0,h1) [2]=(n1,h0) [3]=(n1,h1)
#define LDB4(BX, BOFF) do {                                                    \
    BX[0] = *(const i32x4*)(bPtr + (BOFF));                                    \
    BX[1] = *(const i32x4*)(bPtr + (BOFF) + 1024);                             \
    BX[2] = *(const i32x4*)(bPtr + (BOFF) + 65536);                            \
    BX[3] = *(const i32x4*)(bPtr + (BOFF) + 65536 + 1024);                     \
} while (0)

#define MM8(AX, B0, B1) do {                                                   \
    _Pragma("unroll") for (int m_ = 0; m_ < 4; ++m_) {                         \
        acc[m_][0] = __builtin_amdgcn_mfma_i32_32x32x32_i8(AX[m_], B0, acc[m_][0], 0, 0, 0); \
        acc[m_][1] = __builtin_amdgcn_mfma_i32_32x32x32_i8(AX[m_], B1, acc[m_][1], 0, 0, 0); \
    }                                                                          \
} while (0)

#define STG_A(SS, KOFF) do {                                                   \
    GLDS(aSrc + (KOFF), (SS) * 16384 + L);                                     \
    GLDS(aSrc + (KOFF) + 262144, (SS) * 16384 + 8192 + L);                     \
} while (0)

#define KT(S, SN, SG, BCUR, BNXT, W1, W2, DOSTG, DOB, DONEXT) do {             \
    RD_A4(aO, S, 1);                                                           \
    if (DOB) { LDB4(BNXT, boff); }                                             \
    SB;                                                                        \
    if (DOSTG) { STG_A(SG, koff); }                                            \
    SB;                                                                        \
    W1; SB;                                                                    \
    LGKM4; SB;                                                                 \
    PRIO1; MM8(aE, BCUR[0], BCUR[2]); PRIO0; SB;                               \
    LGKM0; SB;                                                                 \
    W2; SB;                                                                    \
    BARR; SB;                                                                  \
    if (DONEXT) { RD_A4(aE, SN, 0); SB; }                                      \
    PRIO1; MM8(aO, BCUR[1], BCUR[3]); PRIO0; SB;                               \
    koff += 64; boff += 2048;                                                  \
} while (0)

__global__ __launch_bounds__(512, 2) void tl_gemm_i8(
    const s8* __restrict__ A, const s8* __restrict__ BmF,
    const float* __restrict__ qp, const float* __restrict__ bias,
    float* __restrict__ C) {
    __shared__ __attribute__((aligned(128))) char lds[49152];  // 48 KiB, A only

    const int t = threadIdx.x;
    const int wid = t >> 6;
    const int l = t & 63;
    const int wr = wid >> 2;   // 0..1
    const int wc = wid & 3;    // 0..3

    // rect XCD ordering: resident 32 blocks/XCD = 4tm x 8tn rectangle
    const int bid = blockIdx.x;
    const int xc = bid & 7;
    const int j = bid >> 3;                       // 0..127
    const int tm = xc * 4 + ((j >> 3) & 3);
    const int tn = (j >> 5) * 8 + (j & 7);
    const int row0 = tm * 256, col0 = tn * 256;

    // A staging: linear LDS dest byte L holds logical offset L ^ (((L>>7)&3)<<4)
    const int L = t * 16;
    const int off = L ^ (((L >> 7) & 3) << 4);
    const int sr = off >> 6;          // 0..127 (row within half)
    const int kb = off & 63;          // 16-aligned k-byte
    const s8* aSrc = A + (size_t)(row0 + sr) * K_TOT + kb;

    // B fragment pointer: frag(NB, KB) at (NB*64+KB)*1024 + lane*16
    const s8* bPtr = BmF + (size_t)((col0 >> 5) + wc * 2) * 65536 + l * 16;

    // A ds_read lane constants (32x32 fragment: row = l&31, chunk = l>>5)
    const int rl = l & 31, kg = l >> 5;
    const int lrd = rl * 64 + ((kg ^ ((rl >> 1) & 3)) << 4);
    const int wrOff = wr * 8192;      // 128 rows * 64 B

    i32x16 acc[4][2] = {};
    i32x4 aE[4], aO[4], bC[4], bN[4];

    // prologue: glds A(0)->slot0; B(0)->bC; glds A(1)->slot1
    STG_A(0, 0); SB;
    LDB4(bC, 0); SB;
    STG_A(1, 64); SB;
    VMW(6); SB;              // drain gldsA(0); leaves [B(0) 4, gldsA(1) 2]
    BARR; SB;
    RD_A4(aE, 0, 0); SB;

    int koff = 128;   // glds k-byte offset for tile t+2
    int boff = 2048;  // B-frag byte offset for tile t+1
    #pragma unroll 1
    for (int i = 0; i < 5; ++i) {
        KT(0, 1, 2, bC, bN, VMW(8), VMW(6), 1, 1, 1);
        KT(1, 2, 0, bN, bC, VMW(8), VMW(6), 1, 1, 1);
        KT(2, 0, 1, bC, bN, VMW(8), VMW(6), 1, 1, 1);
        KT(0, 1, 2, bN, bC, VMW(8), VMW(6), 1, 1, 1);
        KT(1, 2, 0, bC, bN, VMW(8), VMW(6), 1, 1, 1);
        KT(2, 0, 1, bN, bC, VMW(8), VMW(6), 1, 1, 1);
    }
    KT(0, 1, 0, bC, bN, VMW(6), VMW(4), 0, 1, 1);    // tile 30: loads B(31)
    KT(1, 0, 0, bN, bC, VMW(0), (void)0, 0, 0, 0);   // tile 31

    // epilogue: C = out_scale * acc + bias
    // 32x32 C/D layout: col = l&31, row = (reg&3) + 8*(reg>>2) + 4*(l>>5)
    const float osc = qp[1];
    #pragma unroll
    for (int m_ = 0; m_ < 4; ++m_) {
        const int crow = row0 + wr * 128 + m_ * 32 + kg * 4;
        #pragma unroll
        for (int n_ = 0; n_ < 2; ++n_) {
            const int ccol = col0 + wc * 64 + n_ * 32 + rl;
            const float bv = bias[ccol];
            #pragma unroll
            for (int r = 0; r < 16; ++r) {
                const int row = crow + (r & 3) + 8 * (r >> 2);
                C[(size_t)row * N_TOT + ccol] = (float)acc[m_][n_][r] * osc + bv;
            }
        }
    }
}

extern "C" void kernel_launch(void* const* d_in, const int* in_sizes, int n_in,
                              void* d_out, int out_size, void* d_ws, size_t ws_size,
                              hipStream_t stream) {
    const float* x     = (const float*)d_in[0];
    const float* wgt   = (const float*)d_in[1];
    const float* alpha = (const float*)d_in[2];
    const float* bias  = (const float*)d_in[3];
    float* out = (float*)d_out;

    char* ws = (char*)d_ws;
    double* wsum = (double*)ws;               // 8 KB
    float* xmax  = (float*)(ws + 8192);       // 4 KB
    double* delta = (double*)(ws + 12288);
    float* qp     = (float*)(ws + 12304);     // [0]=127/max, [1]=alpha*max/127
    s8* xb = (s8*)(ws + 16384);               // 16 MB, row-major
    s8* wb = (s8*)(ws + 16384 + (size_t)X_COUNT);  // 16 MB, fragment-ordered

    tl_reduce<<<2048, 256, 0, stream>>>(wgt, x, wsum, xmax);
    tl_finalize<<<1, 256, 0, stream>>>(wsum, xmax, alpha, delta, qp);
    tl_tern_w<<<W_COUNT / (256 * 16), 256, 0, stream>>>(wgt, delta, wb);
    tl_quant_x<<<X_COUNT / (256 * 16), 256, 0, stream>>>(x, qp, xb);
    tl_gemm_i8<<<(M_TOT / 256) * (N_TOT / 256), 512, 0, stream>>>(xb, wb, qp, bias, out);
}